// Round 10
// baseline (6587.056 us; speedup 1.0000x reference)
//
#include <hip/hip_runtime.h>
#include <cstdint>
#include <cstddef>

#define BATCH   8
#define NPTS    16384
#define CFEAT   64
#define NPOINT  2048
#define NSAMPLE 32
#define DIN     124
#define D1      128
#define D2      128
#define D3      256
#define LN_EPS  1e-5f

#define PTS32(F) F(0) F(1) F(2) F(3) F(4) F(5) F(6) F(7) \
                 F(8) F(9) F(10) F(11) F(12) F(13) F(14) F(15) \
                 F(16) F(17) F(18) F(19) F(20) F(21) F(22) F(23) \
                 F(24) F(25) F(26) F(27) F(28) F(29) F(30) F(31)

// ---------------------------------------------------------------------------
// Kernel 1: brute-force FPS, fully register-resident (r10).
// One block per batch, 512 threads, 32 pts/thread. ALL per-point state
// (x,y,z,dist = 128 floats) in named registers: at 512 thr/block = 8 waves/CU
// = 2 waves/SIMD the VGPR budget is 256/wave (r9 showed the hot loop's
// 32 LDS ops/thread/step saturated the LDS pipe at ~3000 cyc/step).
// Value-only f32 argmax (r9-proven): wave shfl_xor max -> wvv[8] -> barrier
// -> redundant 8-way max -> winners (bit-equal, rare) rescan their 32
// register dists for smallest k and atomicMax packed (g_bits<<32 | ~origidx)
// -> smallest original index wins ties (j = t + 512k preserves order).
// Owner thread writes its register coords to cbuf (bit-identical).
// Exact reference f32 math: separate __fsub/__fmul/__fadd (no FMA
// contraction), fminf.
// ---------------------------------------------------------------------------
__attribute__((amdgpu_waves_per_eu(2, 2)))
__global__ __launch_bounds__(512) void fps_kernel(
    const float* __restrict__ xyz, int* __restrict__ fps_idx,
    float* __restrict__ new_xyz)
{
  const int b = blockIdx.x;
  const int t = threadIdx.x;
  const float* X = xyz + (size_t)b * NPTS * 3;

  __shared__ float wvv[8];                       // per-wave f32 max
  __shared__ unsigned long long s_packed;        // (g_bits<<32)|~origidx
  __shared__ float cbuf[3];

#define DECLP(i) float px##i, py##i, pz##i, dd##i;
  PTS32(DECLP)
#undef DECLP

#define LOADP(i) { int j = t + (i << 9);  \
    px##i = X[3 * j + 0];                 \
    py##i = X[3 * j + 1];                 \
    pz##i = X[3 * j + 2];                 \
    dd##i = 1e10f; }
  PTS32(LOADP)
#undef LOADP

  if (t == 0) { cbuf[0] = X[0]; cbuf[1] = X[1]; cbuf[2] = X[2]; s_packed = 0ull; }
  int far = 0;
  __syncthreads();

  for (int s = 0; s < NPOINT; ++s) {
    const float cx = cbuf[0], cy = cbuf[1], cz = cbuf[2];
    if (t == 0) {
      fps_idx[b * NPOINT + s] = far;
      float* o = new_xyz + ((size_t)b * NPOINT + s) * 3;
      o[0] = cx; o[1] = cy; o[2] = cz;
      s_packed = 0ull;                  // reset for this step's atomicMax
    }
    if (s == NPOINT - 1) break;

    // pin state in VGPRs (blocks spill/remat)
    asm volatile("" : "+v"(px0), "+v"(px1), "+v"(px2), "+v"(px3),
                      "+v"(px4), "+v"(px5), "+v"(px6), "+v"(px7),
                      "+v"(px8), "+v"(px9), "+v"(px10), "+v"(px11),
                      "+v"(px12), "+v"(px13), "+v"(px14), "+v"(px15));
    asm volatile("" : "+v"(px16), "+v"(px17), "+v"(px18), "+v"(px19),
                      "+v"(px20), "+v"(px21), "+v"(px22), "+v"(px23),
                      "+v"(px24), "+v"(px25), "+v"(px26), "+v"(px27),
                      "+v"(px28), "+v"(px29), "+v"(px30), "+v"(px31));
    asm volatile("" : "+v"(py0), "+v"(py1), "+v"(py2), "+v"(py3),
                      "+v"(py4), "+v"(py5), "+v"(py6), "+v"(py7),
                      "+v"(py8), "+v"(py9), "+v"(py10), "+v"(py11),
                      "+v"(py12), "+v"(py13), "+v"(py14), "+v"(py15));
    asm volatile("" : "+v"(py16), "+v"(py17), "+v"(py18), "+v"(py19),
                      "+v"(py20), "+v"(py21), "+v"(py22), "+v"(py23),
                      "+v"(py24), "+v"(py25), "+v"(py26), "+v"(py27),
                      "+v"(py28), "+v"(py29), "+v"(py30), "+v"(py31));
    asm volatile("" : "+v"(pz0), "+v"(pz1), "+v"(pz2), "+v"(pz3),
                      "+v"(pz4), "+v"(pz5), "+v"(pz6), "+v"(pz7),
                      "+v"(pz8), "+v"(pz9), "+v"(pz10), "+v"(pz11),
                      "+v"(pz12), "+v"(pz13), "+v"(pz14), "+v"(pz15));
    asm volatile("" : "+v"(pz16), "+v"(pz17), "+v"(pz18), "+v"(pz19),
                      "+v"(pz20), "+v"(pz21), "+v"(pz22), "+v"(pz23),
                      "+v"(pz24), "+v"(pz25), "+v"(pz26), "+v"(pz27),
                      "+v"(pz28), "+v"(pz29), "+v"(pz30), "+v"(pz31));

    float mybest = -1.0f;
#define STEP(i) {                                                        \
    float dx = __fsub_rn(px##i, cx);                                     \
    float dy = __fsub_rn(py##i, cy);                                     \
    float dz = __fsub_rn(pz##i, cz);                                     \
    float d  = __fadd_rn(__fadd_rn(__fmul_rn(dx, dx), __fmul_rn(dy, dy)),\
                         __fmul_rn(dz, dz));                             \
    dd##i = fminf(dd##i, d);                                             \
    mybest = fmaxf(mybest, dd##i); }
    PTS32(STEP)
#undef STEP

    // f32-only wave max
    float wmax = mybest;
#pragma unroll
    for (int off = 32; off >= 1; off >>= 1)
      wmax = fmaxf(wmax, __shfl_xor(wmax, off));
    if ((t & 63) == 0) wvv[t >> 6] = wmax;
    __syncthreads();   // B1

    // stage 2 (redundant, f32): 2x b128 broadcast + max tree
    float4 v0 = *(const float4*)&wvv[0];
    float4 v1 = *(const float4*)&wvv[4];
    float g = fmaxf(fmaxf(fmaxf(v0.x, v0.y), fmaxf(v0.z, v0.w)),
                    fmaxf(fmaxf(v1.x, v1.y), fmaxf(v1.z, v1.w)));

    // winners (bit-exact; usually 1 thread) recover smallest local k
    if (mybest == g) {
      int kk = 32;
#define SCANK(i) if (kk == 32 && dd##i == g) kk = i;
      PTS32(SCANK)
#undef SCANK
      unsigned idx = (unsigned)(t + (kk << 9));
      unsigned long long pk =
          ((unsigned long long)__float_as_uint(g) << 32) | (unsigned)(~idx);
      atomicMax(&s_packed, pk);
    }
    __syncthreads();   // B2

    unsigned long long gp = s_packed;
    int widx = (int)(~(unsigned)(gp & 0xffffffffull)) & 0x3fff;
    far = widx;
    if (t == (widx & 511)) {
      int c = widx >> 9;
#define OWNK(i) if (c == i) { cbuf[0] = px##i; cbuf[1] = py##i; cbuf[2] = pz##i; }
      PTS32(OWNK)
#undef OWNK
    }
    __syncthreads();   // B3
  }
}

// ---------------------------------------------------------------------------
// Kernel 2: exact 32-NN per centroid (r7/r9 version, passing).
// ---------------------------------------------------------------------------
__attribute__((amdgpu_waves_per_eu(2, 2)))
__global__ __launch_bounds__(256) void knn_kernel(
    const float* __restrict__ xyz, const float* __restrict__ new_xyz,
    int* __restrict__ knn_idx)
{
  const int lane = threadIdx.x & 63;
  const int wid  = threadIdx.x >> 6;
  const int gidbase = blockIdx.x * 64 + wid * 16;
  const int b = gidbase / NPOINT;
  const float* X = xyz + (size_t)b * NPTS * 3;

  float cx[16], cy[16], cz[16];
#pragma unroll
  for (int c = 0; c < 16; ++c) {
    const float* p = new_xyz + (size_t)(gidbase + c) * 3;
    cx[c] = p[0]; cy[c] = p[1]; cz[c] = p[2];
  }

  float qd[16]; int qi[16]; float T[16];
#pragma unroll
  for (int c = 0; c < 16; ++c) { qd[c] = 3.4e38f; qi[c] = 0; T[c] = 3.4e38f; }

  for (int base = 0; base < NPTS; base += 64) {
    const int j = base + lane;
    const float x = X[3 * j + 0];
    const float y = X[3 * j + 1];
    const float z = X[3 * j + 2];
#pragma unroll
    for (int c = 0; c < 16; ++c) {
      float dx = __fsub_rn(x, cx[c]);
      float dy = __fsub_rn(y, cy[c]);
      float dz = __fsub_rn(z, cz[c]);
      float v  = __fadd_rn(__fadd_rn(__fmul_rn(dx, dx), __fmul_rn(dy, dy)),
                           __fmul_rn(dz, dz));
      unsigned long long m = __ballot(v < T[c]);
      while (m) {
        int bit = __ffsll(m) - 1;
        m &= m - 1;
        float vb = __shfl(v, bit);
        if (vb < T[c]) {
          int   jb = base + bit;
          float du = __shfl_up(qd[c], 1);
          int   iu = __shfl_up(qi[c], 1);
          bool c2 = (lane > 0) && (vb < du);
          bool c1 = vb < qd[c];
          qd[c] = c2 ? du : (c1 ? vb : qd[c]);
          qi[c] = c2 ? iu : (c1 ? jb : qi[c]);
          T[c] = __shfl(qd[c], 31);
        }
      }
    }
  }
#pragma unroll
  for (int c = 0; c < 16; ++c) {
    if (lane < 32) knn_idx[(size_t)(gidbase + c) * NSAMPLE + lane] = qi[c];
  }
}

// ---------------------------------------------------------------------------
// Kernel 3: gather + NeRF encoding + 3-layer MLP (f32) + max over k
// (r7/r9 version, passing).
// ---------------------------------------------------------------------------
__attribute__((amdgpu_waves_per_eu(4, 4)))
__global__ __launch_bounds__(128) void mlp_kernel(
    const float* __restrict__ xyz, const float* __restrict__ features,
    const float* __restrict__ new_xyz, const int* __restrict__ knn_idx,
    const float* __restrict__ W1, const float* __restrict__ b1,
    const float* __restrict__ g1, const float* __restrict__ be1,
    const float* __restrict__ W2, const float* __restrict__ b2,
    const float* __restrict__ g2, const float* __restrict__ be2,
    const float* __restrict__ W3, const float* __restrict__ b3,
    float* __restrict__ out)
{
  const int g = blockIdx.x;
  const int b = g / NPOINT;
  const int t = threadIdx.x;

  __shared__ float bufT[128 * 36];
  __shared__ int   ki[32];
  __shared__ float cen[3];
  __shared__ float red[32][4][2];
  __shared__ float lnp[32][2];

  if (t < 32) ki[t] = knn_idx[(size_t)g * NSAMPLE + t];
  if (t < 3)  cen[t] = new_xyz[(size_t)g * 3 + t];
  __syncthreads();

  {
    int r = t & 31, cs = (t >> 5) << 4;
    const float* frow = features + ((size_t)b * NPTS + ki[r]) * CFEAT + cs;
#pragma unroll
    for (int u = 0; u < 4; ++u) {
      float4 f = *(const float4*)(frow + 4 * u);
      bufT[(cs + 4 * u + 0) * 36 + r] = f.x;
      bufT[(cs + 4 * u + 1) * 36 + r] = f.y;
      bufT[(cs + 4 * u + 2) * 36 + r] = f.z;
      bufT[(cs + 4 * u + 3) * 36 + r] = f.w;
    }
  }
  if (t < 32) {
    const float* p = xyz + ((size_t)b * NPTS + ki[t]) * 3;
    float rx = p[0] - cen[0];
    float ry = p[1] - cen[1];
    float rz = p[2] - cen[2];
#pragma unroll
    for (int l = 0; l < 10; ++l) {
      float sc = (float)(1 << l);
      float ax = rx * sc, ay = ry * sc, az = rz * sc;
      int base = (64 + l * 6) * 36 + t;
      bufT[base + 0 * 36] = __sinf(ax);
      bufT[base + 1 * 36] = __sinf(ay);
      bufT[base + 2 * 36] = __sinf(az);
      bufT[base + 3 * 36] = __cosf(ax);
      bufT[base + 4 * 36] = __cosf(ay);
      bufT[base + 5 * 36] = __cosf(az);
    }
  }
  __syncthreads();

  float acc[32];

  {
    float bias = b1[t];
#pragma unroll
    for (int r = 0; r < 32; ++r) acc[r] = bias;
    for (int i = 0; i < DIN; ++i) {
      float w = W1[i * D1 + t];
      const float* hr = &bufT[i * 36];
#pragma unroll
      for (int r = 0; r < 32; ++r) acc[r] = fmaf(hr[r], w, acc[r]);
    }
  }
  {
    __syncthreads();
#pragma unroll
    for (int r = 0; r < 32; ++r) bufT[t * 36 + r] = acc[r];
    __syncthreads();
    {
      int r = t & 31, seg = t >> 5;
      float s = 0.f, ss = 0.f;
#pragma unroll
      for (int u = 0; u < 32; ++u) {
        float v = bufT[(seg * 32 + u) * 36 + r];
        s += v; ss = fmaf(v, v, ss);
      }
      red[r][seg][0] = s; red[r][seg][1] = ss;
    }
    __syncthreads();
    if (t < 32) {
      float s  = red[t][0][0] + red[t][1][0] + red[t][2][0] + red[t][3][0];
      float ss = red[t][0][1] + red[t][1][1] + red[t][2][1] + red[t][3][1];
      float m  = s * (1.0f / D1);
      float var = ss * (1.0f / D1) - m * m;
      lnp[t][0] = m;
      lnp[t][1] = rsqrtf(var + LN_EPS);
    }
    __syncthreads();
    float gg = g1[t], bb = be1[t];
#pragma unroll
    for (int r = 0; r < 32; ++r) {
      float v = (acc[r] - lnp[r][0]) * lnp[r][1];
      v = fmaf(v, gg, bb);
      bufT[t * 36 + r] = fmaxf(v, 0.f);
    }
    __syncthreads();
  }

  {
    float bias = b2[t];
#pragma unroll
    for (int r = 0; r < 32; ++r) acc[r] = bias;
    for (int i = 0; i < D1; ++i) {
      float w = W2[i * D2 + t];
      const float* hr = &bufT[i * 36];
#pragma unroll
      for (int r = 0; r < 32; ++r) acc[r] = fmaf(hr[r], w, acc[r]);
    }
  }
  {
    __syncthreads();
#pragma unroll
    for (int r = 0; r < 32; ++r) bufT[t * 36 + r] = acc[r];
    __syncthreads();
    {
      int r = t & 31, seg = t >> 5;
      float s = 0.f, ss = 0.f;
#pragma unroll
      for (int u = 0; u < 32; ++u) {
        float v = bufT[(seg * 32 + u) * 36 + r];
        s += v; ss = fmaf(v, v, ss);
      }
      red[r][seg][0] = s; red[r][seg][1] = ss;
    }
    __syncthreads();
    if (t < 32) {
      float s  = red[t][0][0] + red[t][1][0] + red[t][2][0] + red[t][3][0];
      float ss = red[t][0][1] + red[t][1][1] + red[t][2][1] + red[t][3][1];
      float m  = s * (1.0f / D2);
      float var = ss * (1.0f / D2) - m * m;
      lnp[t][0] = m;
      lnp[t][1] = rsqrtf(var + LN_EPS);
    }
    __syncthreads();
    float gg = g2[t], bb = be2[t];
#pragma unroll
    for (int r = 0; r < 32; ++r) {
      float v = (acc[r] - lnp[r][0]) * lnp[r][1];
      v = fmaf(v, gg, bb);
      bufT[t * 36 + r] = fmaxf(v, 0.f);
    }
    __syncthreads();
  }

  {
    float a0[32], a1[32];
    float bias0 = b3[t], bias1 = b3[t + 128];
#pragma unroll
    for (int r = 0; r < 32; ++r) { a0[r] = bias0; a1[r] = bias1; }
    for (int i = 0; i < D2; ++i) {
      float w0 = W3[i * D3 + t];
      float w1 = W3[i * D3 + t + 128];
      const float* hr = &bufT[i * 36];
#pragma unroll
      for (int r = 0; r < 32; ++r) {
        a0[r] = fmaf(hr[r], w0, a0[r]);
        a1[r] = fmaf(hr[r], w1, a1[r]);
      }
    }
    float m0 = a0[0], m1 = a1[0];
#pragma unroll
    for (int r = 1; r < 32; ++r) { m0 = fmaxf(m0, a0[r]); m1 = fmaxf(m1, a1[r]); }
    float* of = out + (size_t)g * D3;
    of[t] = m0;
    of[t + 128] = m1;
  }
}

// ---------------------------------------------------------------------------
extern "C" void kernel_launch(void* const* d_in, const int* in_sizes, int n_in,
                              void* d_out, int out_size, void* d_ws, size_t ws_size,
                              hipStream_t stream) {
  const float* xyz      = (const float*)d_in[0];
  const float* features = (const float*)d_in[1];
  const float* W1  = (const float*)d_in[2];
  const float* b1  = (const float*)d_in[3];
  const float* g1  = (const float*)d_in[4];
  const float* be1 = (const float*)d_in[5];
  const float* W2  = (const float*)d_in[6];
  const float* b2  = (const float*)d_in[7];
  const float* g2  = (const float*)d_in[8];
  const float* be2 = (const float*)d_in[9];
  const float* W3  = (const float*)d_in[10];
  const float* b3  = (const float*)d_in[11];

  float* new_xyz  = (float*)d_out;
  float* new_feat = (float*)d_out + (size_t)BATCH * NPOINT * 3;

  int* fps_idx = (int*)d_ws;
  int* knn_idx = fps_idx + BATCH * NPOINT;

  fps_kernel<<<dim3(BATCH), dim3(512), 0, stream>>>(xyz, fps_idx, new_xyz);
  knn_kernel<<<dim3((BATCH * NPOINT) / 64), dim3(256), 0, stream>>>(xyz, new_xyz, knn_idx);
  mlp_kernel<<<dim3(BATCH * NPOINT), dim3(128), 0, stream>>>(
      xyz, features, new_xyz, knn_idx,
      W1, b1, g1, be1, W2, b2, g2, be2, W3, b3, new_feat);
}

// Round 11
// 5873.037 us; speedup vs baseline: 1.1216x; 1.1216x over previous
//
#include <hip/hip_runtime.h>
#include <cstdint>
#include <cstddef>

#define BATCH   8
#define NPTS    16384
#define CFEAT   64
#define NPOINT  2048
#define NSAMPLE 32
#define DIN     124
#define D1      128
#define D2      128
#define D3      256
#define LN_EPS  1e-5f

#define PTS16(F) F(0) F(1) F(2) F(3) F(4) F(5) F(6) F(7) \
                 F(8) F(9) F(10) F(11) F(12) F(13) F(14) F(15)

// ---------------------------------------------------------------------------
// Kernel 1: brute-force FPS, b128-packed LDS dist (r11).
// r9 structure (1024 thr, 16 pts/thread, coords in 48 asm-pinned regs,
// value-only f32 argmax) with ONE change: the running min-dist lives as
// float4 s_mind4[pack][tid] and is accessed via 4x ds_read_b128 +
// 4x ds_write_b128 per step instead of 16+16 b32 ops. r9's LDS pipe cost
// (~3000 cyc/step, the dominant term) halves to ~1540.
// Index/decision semantics identical to r9 (bit-exact): point (t,i) is
// j = t + (i<<10); winner rescan descending-overwrite -> smallest i;
// atomicMax packed (g_bits<<32 | ~j) -> smallest original j on ties.
// Exact reference f32 math: __fsub/__fmul/__fadd (no contraction), fminf.
// ---------------------------------------------------------------------------
__attribute__((amdgpu_waves_per_eu(4, 4)))
__global__ __launch_bounds__(1024) void fps_kernel(
    const float* __restrict__ xyz, int* __restrict__ fps_idx,
    float* __restrict__ new_xyz)
{
  const int b = blockIdx.x;
  const int t = threadIdx.x;
  const float* X = xyz + (size_t)b * NPTS * 3;

  __shared__ float4 s_mind4[4][1024];            // 64 KB, pack p = dists i=4p..4p+3
  __shared__ float wvv[16];                      // per-wave f32 max
  __shared__ unsigned long long s_packed;        // (g_bits<<32)|~origidx
  __shared__ float cbuf[3];

#define DECLP(i) float px##i, py##i, pz##i;
  PTS16(DECLP)
#undef DECLP

#define LOADP(i) { int j = t + (i << 10);  \
    px##i = X[3 * j + 0];                  \
    py##i = X[3 * j + 1];                  \
    pz##i = X[3 * j + 2]; }
  PTS16(LOADP)
#undef LOADP
  s_mind4[0][t] = make_float4(1e10f, 1e10f, 1e10f, 1e10f);
  s_mind4[1][t] = make_float4(1e10f, 1e10f, 1e10f, 1e10f);
  s_mind4[2][t] = make_float4(1e10f, 1e10f, 1e10f, 1e10f);
  s_mind4[3][t] = make_float4(1e10f, 1e10f, 1e10f, 1e10f);

  if (t == 0) { cbuf[0] = X[0]; cbuf[1] = X[1]; cbuf[2] = X[2]; s_packed = 0ull; }
  int far = 0;
  __syncthreads();

  for (int s = 0; s < NPOINT; ++s) {
    const float cx = cbuf[0], cy = cbuf[1], cz = cbuf[2];
    if (t == 0) {
      fps_idx[b * NPOINT + s] = far;
      float* o = new_xyz + ((size_t)b * NPOINT + s) * 3;
      o[0] = cx; o[1] = cy; o[2] = cz;
      s_packed = 0ull;                  // reset for this step's atomicMax
    }
    if (s == NPOINT - 1) break;

    // pin coords in VGPRs (blocks spill/remat; r9-proven)
    asm volatile("" : "+v"(px0), "+v"(px1), "+v"(px2), "+v"(px3),
                      "+v"(px4), "+v"(px5), "+v"(px6), "+v"(px7),
                      "+v"(px8), "+v"(px9), "+v"(px10), "+v"(px11),
                      "+v"(px12), "+v"(px13), "+v"(px14), "+v"(px15));
    asm volatile("" : "+v"(py0), "+v"(py1), "+v"(py2), "+v"(py3),
                      "+v"(py4), "+v"(py5), "+v"(py6), "+v"(py7),
                      "+v"(py8), "+v"(py9), "+v"(py10), "+v"(py11),
                      "+v"(py12), "+v"(py13), "+v"(py14), "+v"(py15));
    asm volatile("" : "+v"(pz0), "+v"(pz1), "+v"(pz2), "+v"(pz3),
                      "+v"(pz4), "+v"(pz5), "+v"(pz6), "+v"(pz7),
                      "+v"(pz8), "+v"(pz9), "+v"(pz10), "+v"(pz11),
                      "+v"(pz12), "+v"(pz13), "+v"(pz14), "+v"(pz15));

    float mybest = -1.0f;
#define DIST(i) ({                                                       \
    float dx_ = __fsub_rn(px##i, cx);                                    \
    float dy_ = __fsub_rn(py##i, cy);                                    \
    float dz_ = __fsub_rn(pz##i, cz);                                    \
    __fadd_rn(__fadd_rn(__fmul_rn(dx_, dx_), __fmul_rn(dy_, dy_)),       \
              __fmul_rn(dz_, dz_)); })
#define PACKSTEP(p, i0, i1, i2, i3) {                                    \
    float4 dv = s_mind4[p][t];                                           \
    dv.x = fminf(dv.x, DIST(i0));                                        \
    dv.y = fminf(dv.y, DIST(i1));                                        \
    dv.z = fminf(dv.z, DIST(i2));                                        \
    dv.w = fminf(dv.w, DIST(i3));                                        \
    s_mind4[p][t] = dv;                                                  \
    mybest = fmaxf(mybest, fmaxf(fmaxf(dv.x, dv.y), fmaxf(dv.z, dv.w))); }
    PACKSTEP(0, 0, 1, 2, 3)
    PACKSTEP(1, 4, 5, 6, 7)
    PACKSTEP(2, 8, 9, 10, 11)
    PACKSTEP(3, 12, 13, 14, 15)
#undef PACKSTEP
#undef DIST

    // f32-only wave max
    float wmax = mybest;
#pragma unroll
    for (int off = 32; off >= 1; off >>= 1)
      wmax = fmaxf(wmax, __shfl_xor(wmax, off));
    if ((t & 63) == 0) wvv[t >> 6] = wmax;
    __syncthreads();   // B1

    // stage 2 (redundant, f32): 4x b128 broadcast + max tree
    float4 v0 = *(const float4*)&wvv[0];
    float4 v1 = *(const float4*)&wvv[4];
    float4 v2 = *(const float4*)&wvv[8];
    float4 v3 = *(const float4*)&wvv[12];
    float g = fmaxf(
        fmaxf(fmaxf(fmaxf(v0.x, v0.y), fmaxf(v0.z, v0.w)),
              fmaxf(fmaxf(v1.x, v1.y), fmaxf(v1.z, v1.w))),
        fmaxf(fmaxf(fmaxf(v2.x, v2.y), fmaxf(v2.z, v2.w)),
              fmaxf(fmaxf(v3.x, v3.y), fmaxf(v3.z, v3.w))));

    // winners (bit-exact; usually 1 thread): descending-overwrite scan
    // over packs/components -> smallest i on per-thread ties
    if (mybest == g) {
      int kk = 16;
#pragma unroll
      for (int p = 3; p >= 0; --p) {
        float4 dv = s_mind4[p][t];
        if (dv.w == g) kk = 4 * p + 3;
        if (dv.z == g) kk = 4 * p + 2;
        if (dv.y == g) kk = 4 * p + 1;
        if (dv.x == g) kk = 4 * p + 0;
      }
      unsigned idx = (unsigned)(t + (kk << 10));
      unsigned long long pk =
          ((unsigned long long)__float_as_uint(g) << 32) | (unsigned)(~idx);
      atomicMax(&s_packed, pk);
    }
    __syncthreads();   // B2

    unsigned long long gp = s_packed;
    int widx = (int)(~(unsigned)(gp & 0xffffffffull)) & 0x3fff;
    far = widx;
    if (t == (widx & 1023)) {
      int c = widx >> 10;
#define OWNK(i) if (c == i) { cbuf[0] = px##i; cbuf[1] = py##i; cbuf[2] = pz##i; }
      PTS16(OWNK)
#undef OWNK
    }
    __syncthreads();   // B3
  }
}

// ---------------------------------------------------------------------------
// Kernel 2: exact 32-NN per centroid (r7/r9 version, passing).
// ---------------------------------------------------------------------------
__attribute__((amdgpu_waves_per_eu(2, 2)))
__global__ __launch_bounds__(256) void knn_kernel(
    const float* __restrict__ xyz, const float* __restrict__ new_xyz,
    int* __restrict__ knn_idx)
{
  const int lane = threadIdx.x & 63;
  const int wid  = threadIdx.x >> 6;
  const int gidbase = blockIdx.x * 64 + wid * 16;
  const int b = gidbase / NPOINT;
  const float* X = xyz + (size_t)b * NPTS * 3;

  float cx[16], cy[16], cz[16];
#pragma unroll
  for (int c = 0; c < 16; ++c) {
    const float* p = new_xyz + (size_t)(gidbase + c) * 3;
    cx[c] = p[0]; cy[c] = p[1]; cz[c] = p[2];
  }

  float qd[16]; int qi[16]; float T[16];
#pragma unroll
  for (int c = 0; c < 16; ++c) { qd[c] = 3.4e38f; qi[c] = 0; T[c] = 3.4e38f; }

  for (int base = 0; base < NPTS; base += 64) {
    const int j = base + lane;
    const float x = X[3 * j + 0];
    const float y = X[3 * j + 1];
    const float z = X[3 * j + 2];
#pragma unroll
    for (int c = 0; c < 16; ++c) {
      float dx = __fsub_rn(x, cx[c]);
      float dy = __fsub_rn(y, cy[c]);
      float dz = __fsub_rn(z, cz[c]);
      float v  = __fadd_rn(__fadd_rn(__fmul_rn(dx, dx), __fmul_rn(dy, dy)),
                           __fmul_rn(dz, dz));
      unsigned long long m = __ballot(v < T[c]);
      while (m) {
        int bit = __ffsll(m) - 1;
        m &= m - 1;
        float vb = __shfl(v, bit);
        if (vb < T[c]) {
          int   jb = base + bit;
          float du = __shfl_up(qd[c], 1);
          int   iu = __shfl_up(qi[c], 1);
          bool c2 = (lane > 0) && (vb < du);
          bool c1 = vb < qd[c];
          qd[c] = c2 ? du : (c1 ? vb : qd[c]);
          qi[c] = c2 ? iu : (c1 ? jb : qi[c]);
          T[c] = __shfl(qd[c], 31);
        }
      }
    }
  }
#pragma unroll
  for (int c = 0; c < 16; ++c) {
    if (lane < 32) knn_idx[(size_t)(gidbase + c) * NSAMPLE + lane] = qi[c];
  }
}

// ---------------------------------------------------------------------------
// Kernel 3: gather + NeRF encoding + 3-layer MLP (f32) + max over k
// (r7/r9 version, passing).
// ---------------------------------------------------------------------------
__attribute__((amdgpu_waves_per_eu(4, 4)))
__global__ __launch_bounds__(128) void mlp_kernel(
    const float* __restrict__ xyz, const float* __restrict__ features,
    const float* __restrict__ new_xyz, const int* __restrict__ knn_idx,
    const float* __restrict__ W1, const float* __restrict__ b1,
    const float* __restrict__ g1, const float* __restrict__ be1,
    const float* __restrict__ W2, const float* __restrict__ b2,
    const float* __restrict__ g2, const float* __restrict__ be2,
    const float* __restrict__ W3, const float* __restrict__ b3,
    float* __restrict__ out)
{
  const int g = blockIdx.x;
  const int b = g / NPOINT;
  const int t = threadIdx.x;

  __shared__ float bufT[128 * 36];
  __shared__ int   ki[32];
  __shared__ float cen[3];
  __shared__ float red[32][4][2];
  __shared__ float lnp[32][2];

  if (t < 32) ki[t] = knn_idx[(size_t)g * NSAMPLE + t];
  if (t < 3)  cen[t] = new_xyz[(size_t)g * 3 + t];
  __syncthreads();

  {
    int r = t & 31, cs = (t >> 5) << 4;
    const float* frow = features + ((size_t)b * NPTS + ki[r]) * CFEAT + cs;
#pragma unroll
    for (int u = 0; u < 4; ++u) {
      float4 f = *(const float4*)(frow + 4 * u);
      bufT[(cs + 4 * u + 0) * 36 + r] = f.x;
      bufT[(cs + 4 * u + 1) * 36 + r] = f.y;
      bufT[(cs + 4 * u + 2) * 36 + r] = f.z;
      bufT[(cs + 4 * u + 3) * 36 + r] = f.w;
    }
  }
  if (t < 32) {
    const float* p = xyz + ((size_t)b * NPTS + ki[t]) * 3;
    float rx = p[0] - cen[0];
    float ry = p[1] - cen[1];
    float rz = p[2] - cen[2];
#pragma unroll
    for (int l = 0; l < 10; ++l) {
      float sc = (float)(1 << l);
      float ax = rx * sc, ay = ry * sc, az = rz * sc;
      int base = (64 + l * 6) * 36 + t;
      bufT[base + 0 * 36] = __sinf(ax);
      bufT[base + 1 * 36] = __sinf(ay);
      bufT[base + 2 * 36] = __sinf(az);
      bufT[base + 3 * 36] = __cosf(ax);
      bufT[base + 4 * 36] = __cosf(ay);
      bufT[base + 5 * 36] = __cosf(az);
    }
  }
  __syncthreads();

  float acc[32];

  {
    float bias = b1[t];
#pragma unroll
    for (int r = 0; r < 32; ++r) acc[r] = bias;
    for (int i = 0; i < DIN; ++i) {
      float w = W1[i * D1 + t];
      const float* hr = &bufT[i * 36];
#pragma unroll
      for (int r = 0; r < 32; ++r) acc[r] = fmaf(hr[r], w, acc[r]);
    }
  }
  {
    __syncthreads();
#pragma unroll
    for (int r = 0; r < 32; ++r) bufT[t * 36 + r] = acc[r];
    __syncthreads();
    {
      int r = t & 31, seg = t >> 5;
      float s = 0.f, ss = 0.f;
#pragma unroll
      for (int u = 0; u < 32; ++u) {
        float v = bufT[(seg * 32 + u) * 36 + r];
        s += v; ss = fmaf(v, v, ss);
      }
      red[r][seg][0] = s; red[r][seg][1] = ss;
    }
    __syncthreads();
    if (t < 32) {
      float s  = red[t][0][0] + red[t][1][0] + red[t][2][0] + red[t][3][0];
      float ss = red[t][0][1] + red[t][1][1] + red[t][2][1] + red[t][3][1];
      float m  = s * (1.0f / D1);
      float var = ss * (1.0f / D1) - m * m;
      lnp[t][0] = m;
      lnp[t][1] = rsqrtf(var + LN_EPS);
    }
    __syncthreads();
    float gg = g1[t], bb = be1[t];
#pragma unroll
    for (int r = 0; r < 32; ++r) {
      float v = (acc[r] - lnp[r][0]) * lnp[r][1];
      v = fmaf(v, gg, bb);
      bufT[t * 36 + r] = fmaxf(v, 0.f);
    }
    __syncthreads();
  }

  {
    float bias = b2[t];
#pragma unroll
    for (int r = 0; r < 32; ++r) acc[r] = bias;
    for (int i = 0; i < D1; ++i) {
      float w = W2[i * D2 + t];
      const float* hr = &bufT[i * 36];
#pragma unroll
      for (int r = 0; r < 32; ++r) acc[r] = fmaf(hr[r], w, acc[r]);
    }
  }
  {
    __syncthreads();
#pragma unroll
    for (int r = 0; r < 32; ++r) bufT[t * 36 + r] = acc[r];
    __syncthreads();
    {
      int r = t & 31, seg = t >> 5;
      float s = 0.f, ss = 0.f;
#pragma unroll
      for (int u = 0; u < 32; ++u) {
        float v = bufT[(seg * 32 + u) * 36 + r];
        s += v; ss = fmaf(v, v, ss);
      }
      red[r][seg][0] = s; red[r][seg][1] = ss;
    }
    __syncthreads();
    if (t < 32) {
      float s  = red[t][0][0] + red[t][1][0] + red[t][2][0] + red[t][3][0];
      float ss = red[t][0][1] + red[t][1][1] + red[t][2][1] + red[t][3][1];
      float m  = s * (1.0f / D2);
      float var = ss * (1.0f / D2) - m * m;
      lnp[t][0] = m;
      lnp[t][1] = rsqrtf(var + LN_EPS);
    }
    __syncthreads();
    float gg = g2[t], bb = be2[t];
#pragma unroll
    for (int r = 0; r < 32; ++r) {
      float v = (acc[r] - lnp[r][0]) * lnp[r][1];
      v = fmaf(v, gg, bb);
      bufT[t * 36 + r] = fmaxf(v, 0.f);
    }
    __syncthreads();
  }

  {
    float a0[32], a1[32];
    float bias0 = b3[t], bias1 = b3[t + 128];
#pragma unroll
    for (int r = 0; r < 32; ++r) { a0[r] = bias0; a1[r] = bias1; }
    for (int i = 0; i < D2; ++i) {
      float w0 = W3[i * D3 + t];
      float w1 = W3[i * D3 + t + 128];
      const float* hr = &bufT[i * 36];
#pragma unroll
      for (int r = 0; r < 32; ++r) {
        a0[r] = fmaf(hr[r], w0, a0[r]);
        a1[r] = fmaf(hr[r], w1, a1[r]);
      }
    }
    float m0 = a0[0], m1 = a1[0];
#pragma unroll
    for (int r = 1; r < 32; ++r) { m0 = fmaxf(m0, a0[r]); m1 = fmaxf(m1, a1[r]); }
    float* of = out + (size_t)g * D3;
    of[t] = m0;
    of[t + 128] = m1;
  }
}

// ---------------------------------------------------------------------------
extern "C" void kernel_launch(void* const* d_in, const int* in_sizes, int n_in,
                              void* d_out, int out_size, void* d_ws, size_t ws_size,
                              hipStream_t stream) {
  const float* xyz      = (const float*)d_in[0];
  const float* features = (const float*)d_in[1];
  const float* W1  = (const float*)d_in[2];
  const float* b1  = (const float*)d_in[3];
  const float* g1  = (const float*)d_in[4];
  const float* be1 = (const float*)d_in[5];
  const float* W2  = (const float*)d_in[6];
  const float* b2  = (const float*)d_in[7];
  const float* g2  = (const float*)d_in[8];
  const float* be2 = (const float*)d_in[9];
  const float* W3  = (const float*)d_in[10];
  const float* b3  = (const float*)d_in[11];

  float* new_xyz  = (float*)d_out;
  float* new_feat = (float*)d_out + (size_t)BATCH * NPOINT * 3;

  int* fps_idx = (int*)d_ws;
  int* knn_idx = fps_idx + BATCH * NPOINT;

  fps_kernel<<<dim3(BATCH), dim3(1024), 0, stream>>>(xyz, fps_idx, new_xyz);
  knn_kernel<<<dim3((BATCH * NPOINT) / 64), dim3(256), 0, stream>>>(xyz, new_xyz, knn_idx);
  mlp_kernel<<<dim3(BATCH * NPOINT), dim3(128), 0, stream>>>(
      xyz, features, new_xyz, knn_idx,
      W1, b1, g1, be1, W2, b2, g2, be2, W3, b3, new_feat);
}